// Round 11
// baseline (231.065 us; speedup 1.0000x reference)
//
#include <hip/hip_runtime.h>
#include <math.h>

#define H 64
#define W 64
#define C 256
#define O 256
#define CK 2304
#define NB 8
#define HWSZ 4096            // H*W

typedef __attribute__((ext_vector_type(8))) short short8;
typedef __attribute__((ext_vector_type(4))) float floatx4;
typedef __attribute__((ext_vector_type(4))) unsigned uintx4;
typedef __attribute__((ext_vector_type(2))) float f32x2;

// swizzle giving uniform bank-group coverage in every 16-lane b128 phase
// for both the sampling-write map and the MFMA-read map
#define FSWZ(n) ((((n) & 3) << 1) | (((n) >> 2) & 1))

__device__ __forceinline__ float lo2f(unsigned u) {
  return __builtin_bit_cast(float, u << 16);
}
__device__ __forceinline__ float hi2f(unsigned u) {
  return __builtin_bit_cast(float, u & 0xffff0000u);
}
// unpack u32 of 2 bf16 -> f32x2 {lo, hi}
__device__ __forceinline__ f32x2 up2(unsigned u) {
  return (f32x2){lo2f(u), hi2f(u)};
}
// pack two fp32 -> bf16 pair, round-half-up (prep kernels)
__device__ __forceinline__ unsigned pk2bf(float v0, float v1) {
  unsigned a = __builtin_bit_cast(unsigned, v0);
  unsigned b = __builtin_bit_cast(unsigned, v1);
  return ((a + 0x8000u) >> 16) | ((b + 0x8000u) & 0xffff0000u);
}

// ---- packed fp32 math + hw bf16 pack (hipcc won't emit these itself) ----
__device__ __forceinline__ f32x2 pk_mul(f32x2 a, f32x2 b) {
  f32x2 d;
  asm("v_pk_mul_f32 %0, %1, %2" : "=v"(d) : "v"(a), "v"(b));
  return d;
}
__device__ __forceinline__ f32x2 pk_fma(f32x2 a, f32x2 b, f32x2 c) {
  f32x2 d;
  asm("v_pk_fma_f32 %0, %1, %2, %3" : "=v"(d) : "v"(a), "v"(b), "v"(c));
  return d;
}
__device__ __forceinline__ unsigned cvtpk(f32x2 a) {
  unsigned d;
  asm("v_cvt_pk_bf16_f32 %0, %1, %2" : "=v"(d) : "v"(a[0]), "v"(a[1]));
  return d;
}

// ---------------- prep_all2: transpose + weight packs + BN, ONE launch ----
// region 0: bid < 256 : transpose x NCHW fp32 -> NHWC bf16
// region 1: bid < 400 : prep main weight -> MFMA-A fragments
// region 2: bid < 418 : prep offset weight -> A fragments (M padded 27->32)
// region 3: bid ==418 : folded BN
__global__ __launch_bounds__(512) void prep_all2(
    const float* __restrict__ x, const float* __restrict__ weight,
    const float* __restrict__ w_off, const float* __restrict__ bias,
    const float* __restrict__ gamma, const float* __restrict__ beta,
    const float* __restrict__ run_mean, const float* __restrict__ run_var,
    unsigned short* __restrict__ xt, unsigned short* __restrict__ wb,
    unsigned short* __restrict__ wob, float* __restrict__ invsh) {
  __shared__ unsigned tile[16384];       // [2][128][64] u32, 64 KB
  int bid = blockIdx.x;
  int tid = threadIdx.x;

  if (bid < 256) {
    int b = bid >> 5;
    int yg = bid & 31;
    int y0 = yg * 2;
    // ---- phase 1: load ch-pair x 2 rows, pack bf16 pairs into LDS ----
#pragma unroll
    for (int j = 0; j < 4; ++j) {
      int e = tid + 512 * j;             // (cp 0..127) x (xx4 0..15)
      int xx4 = e & 15;
      int cp = e >> 4;
      const float* p0 = x + ((size_t)b * C + 2 * cp) * HWSZ + y0 * W + xx4 * 4;
      floatx4 f00 = *reinterpret_cast<const floatx4*>(p0);
      floatx4 f01 = *reinterpret_cast<const floatx4*>(p0 + W);
      floatx4 f10 = *reinterpret_cast<const floatx4*>(p0 + HWSZ);
      floatx4 f11 = *reinterpret_cast<const floatx4*>(p0 + HWSZ + W);
      int sw = cp & 31;
#pragma unroll
      for (int k = 0; k < 4; ++k) {
        int px = xx4 * 4 + k;
        tile[cp * 64 + (px ^ sw)] = pk2bf(f00[k], f10[k]);
        tile[8192 + cp * 64 + (px ^ sw)] = pk2bf(f01[k], f11[k]);
      }
    }
    __syncthreads();
    // ---- phase 2: contiguous 32 KB store of 2 full NHWC rows ----
    unsigned short* xo = xt + ((size_t)(b * 64 + y0) << 14);
#pragma unroll
    for (int j = 0; j < 8; ++j) {
      int e = tid + 512 * j;             // (r 0..1) x (xx 0..63) x (cq 0..31)
      int cq = e & 31;
      int xx = (e >> 5) & 63;
      int r = e >> 11;
      unsigned u[4];
#pragma unroll
      for (int kk = 0; kk < 4; ++kk) {
        int cpv = cq * 4 + kk;
        u[kk] = tile[r * 8192 + cpv * 64 + (xx ^ (cpv & 31))];
      }
      uint4 v = {u[0], u[1], u[2], u[3]};
      *reinterpret_cast<uint4*>(xo + (r << 14) + (xx << 8) + (cq << 3)) = v;
    }
  } else if (bid < 400) {
    int idx = (bid - 256) * 512 + tid;
    int d0 = idx * 8;
    int lane = idx & 63;
    int mt = (idx >> 6) & 15;
    int ks = idx >> 10;
    int o = mt * 16 + (lane & 15);
    int kn0 = ks * 32 + (lane >> 4) * 8;
    int tap = kn0 >> 8;
    int c0 = kn0 & 255;
    const float* wsrc = weight + o * CK + c0 * 9 + tap;
    unsigned pk[4];
#pragma unroll
    for (int p = 0; p < 4; ++p)
      pk[p] = pk2bf(wsrc[(2 * p) * 9], wsrc[(2 * p + 1) * 9]);
    uint4 v = {pk[0], pk[1], pk[2], pk[3]};
    *reinterpret_cast<uint4*>(wb + d0) = v;
  } else if (bid < 418) {
    int idx = (bid - 400) * 512 + tid;
    int d0 = idx * 8;
    int lane = idx & 63;
    int mt = (idx >> 6) & 1;
    int ks = idx >> 7;
    int o = mt * 16 + (lane & 15);
    int kn0 = ks * 32 + (lane >> 4) * 8;
    int tap = kn0 >> 8;
    int c0 = kn0 & 255;
    uint4 v;
    if (o < 27) {
      const float* wsrc = w_off + o * CK + c0 * 9 + tap;
      unsigned pk[4];
#pragma unroll
      for (int p = 0; p < 4; ++p)
        pk[p] = pk2bf(wsrc[(2 * p) * 9], wsrc[(2 * p + 1) * 9]);
      v = (uint4){pk[0], pk[1], pk[2], pk[3]};
    } else {
      v = (uint4){0, 0, 0, 0};
    }
    *reinterpret_cast<uint4*>(wob + d0) = v;
  } else {
    if (tid < 256) {
      int o = tid;
      float inv = gamma[o] * rsqrtf(run_var[o] + 1e-5f);
      invsh[o] = inv;
      invsh[O + o] = beta[o] + (bias[o] - run_mean[o]) * inv;
    }
  }
}

// ---- sampling, issue half: 8 corner loads (2 c-blocks x 4 corners) ------
__device__ __forceinline__ void issue_half(
    const unsigned short* __restrict__ p, int scb, int half,
    uintx4 (&u00)[2], uintx4 (&u01)[2], uintx4 (&u10)[2], uintx4 (&u11)[2]) {
#pragma unroll
  for (int j = 0; j < 2; ++j) {
    int co = (((half * 2 + j) << 3) | scb) << 3;
    u00[j] = *reinterpret_cast<const uintx4*>(p + co);
    u01[j] = *reinterpret_cast<const uintx4*>(p + 256 + co);
    u10[j] = *reinterpret_cast<const uintx4*>(p + 16384 + co);
    u11[j] = *reinterpret_cast<const uintx4*>(p + 16640 + co);
  }
}

// ---- sampling, finish half: packed bilinear + hw bf16 pack + LDS write --
__device__ __forceinline__ void finish_half(
    short* __restrict__ colbuf, int sn, int scb, int half,
    f32x2 w00, f32x2 w01, f32x2 w10, f32x2 w11,
    const uintx4 (&u00)[2], const uintx4 (&u01)[2],
    const uintx4 (&u10)[2], const uintx4 (&u11)[2]) {
#pragma unroll
  for (int j = 0; j < 2; ++j) {
    int cbw = ((half * 2 + j) << 3) | scb;
    uintx4 res;
#pragma unroll
    for (int jd = 0; jd < 4; ++jd) {
      f32x2 a = pk_mul(up2(u00[j][jd]), w00);
      a = pk_fma(up2(u01[j][jd]), w01, a);
      a = pk_fma(up2(u10[j][jd]), w10, a);
      a = pk_fma(up2(u11[j][jd]), w11, a);
      res[jd] = cvtpk(a);
    }
    int pos = (cbw ^ FSWZ(sn)) & 31;
    *reinterpret_cast<uintx4*>(&colbuf[(sn << 8) + (pos << 3)]) = res;
  }
}

// ---- MFMA half-tap: 4 k-steps, 2 m-tiles x 4 n-tiles per wave -----------
__device__ __forceinline__ void mfma_half(
    int tap, int half, const unsigned short* __restrict__ wb,
    const short* __restrict__ colbuf, int wvid, int lane, int q, int lm,
    floatx4 (&acc)[2][4]) {
  __builtin_amdgcn_s_setprio(1);
#pragma unroll
  for (int s2 = 0; s2 < 4; ++s2) {
    int s = half * 4 + s2;
    int ks = tap * 8 + s;
    short8 afrag[2];
#pragma unroll
    for (int a = 0; a < 2; ++a)
      afrag[a] = *reinterpret_cast<const short8*>(
          wb + (((ks * 16 + wvid * 2 + a) * 64 + lane) << 3));
    short8 bfrag[4];
#pragma unroll
    for (int u = 0; u < 4; ++u) {
      int nn = u * 16 + lm;
      int pos = ((s * 4 + q) ^ FSWZ(nn)) & 31;
      bfrag[u] = *reinterpret_cast<const short8*>(&colbuf[(nn << 8) + (pos << 3)]);
    }
#pragma unroll
    for (int a = 0; a < 2; ++a)
#pragma unroll
      for (int u = 0; u < 4; ++u)
        acc[a][u] = __builtin_amdgcn_mfma_f32_16x16x32_bf16(
            afrag[a], bfrag[u], acc[a][u], 0, 0, 0);
  }
  __builtin_amdgcn_s_setprio(0);
}

// ---------------- Fused kernel: offset conv + deform sample + GEMM + BN ---
// grid (b, h), 512 threads (8 waves).  Block = row h: 64 px x 256 out.
// T14 async-STAGE pipeline (r3 structure, correctness-proven) now run
// under the (512,2) register regime that removed r3's spills: corner
// loads issued BEFORE a 32-MFMA half-cluster, bilinear+LDS-write after;
// double-buffered cols; ONE barrier per tap.
__global__ __launch_bounds__(512, 2) void deform_mfma_kernel(
    const unsigned short* __restrict__ xt, const unsigned short* __restrict__ wob,
    const float* __restrict__ b_off, const unsigned short* __restrict__ wb,
    const float* __restrict__ invsh, float* __restrict__ out) {
  __shared__ short cols[2][64 * 256];    // 64 KB, FSWZ-swizzled, double-buffered
  __shared__ int sbase[576];
  __shared__ float s00[576], s01[576], s10[576], s11[576];
  // offset-conv result overlaid on cols[0] (dead after phase A2; barriers
  // separate every conflicting access)
  float* sm_om = reinterpret_cast<float*>(&cols[0][0]);   // 27*64 floats

  int tid = threadIdx.x;
  int lane = tid & 63;
  int wvid = tid >> 6;                   // 0..7
  int q = lane >> 4;
  int lm = lane & 15;
  int b = blockIdx.x;
  int h = blockIdx.y;
  const unsigned short* xtb = xt + ((size_t)b << 20);

  // ======== Phase A: offset conv, 4 active waves, wave = 1 mt x 2 nt
  if (wvid < 4) {
    int mt = wvid & 1;
    int nh = wvid >> 1;                  // px quarter-pair
    floatx4 a0[2];
    a0[0] = (floatx4){0.f, 0.f, 0.f, 0.f};
    a0[1] = (floatx4){0.f, 0.f, 0.f, 0.f};
    int pxu[2];
    pxu[0] = (nh * 2 + 0) * 16 + lm;
    pxu[1] = (nh * 2 + 1) * 16 + lm;
    for (int tap = 0; tap < 9; ++tap) {
      int yy = h - 1 + tap / 3;
      bool vy = (yy >= 0) && (yy < H);
      const unsigned short* bp[2];
      bool vv[2];
#pragma unroll
      for (int u = 0; u < 2; ++u) {
        int xx = pxu[u] - 1 + tap % 3;
        vv[u] = vy && (xx >= 0) && (xx < W);
        bp[u] = xtb + ((((yy & 63) << 6) + (xx & 63)) << 8) + q * 8;
      }
#pragma unroll
      for (int s = 0; s < 8; ++s) {
        int ks = tap * 8 + s;
        short8 afrag = *reinterpret_cast<const short8*>(
            wob + (((ks * 2 + mt) * 64 + lane) << 3));
#pragma unroll
        for (int u = 0; u < 2; ++u) {
          short8 bfrag;
          if (vv[u])
            bfrag = *reinterpret_cast<const short8*>(bp[u] + s * 32);
          else
            bfrag = (short8){0, 0, 0, 0, 0, 0, 0, 0};
          a0[u] = __builtin_amdgcn_mfma_f32_16x16x32_bf16(afrag, bfrag, a0[u], 0, 0, 0);
        }
      }
    }
#pragma unroll
    for (int u = 0; u < 2; ++u)
#pragma unroll
      for (int r = 0; r < 4; ++r) {
        int o = mt * 16 + q * 4 + r;
        if (o < 27) sm_om[o * 64 + pxu[u]] = a0[u][r] + b_off[o];
      }
  }
  __syncthreads();

  // ======== Phase A2: separable clamp-swap bilinear tables (9 taps x 64 px)
  for (int e = tid; e < 576; e += 512) {
    int n = e & 63;
    int k = e >> 6;
    float oy = sm_om[k * 64 + n];
    float ox = sm_om[(9 + k) * 64 + n];
    float mv = sm_om[(18 + k) * 64 + n];
    float m = 1.0f / (1.0f + __expf(-mv));
    float py = (float)(h - 1 + k / 3) + oy;
    float px = (float)(n - 1 + k % 3) + ox;
    float yf = floorf(py), xf = floorf(px);
    int y0 = (int)yf, x0 = (int)xf;
    float fy = py - yf, fx = px - xf;
    float r0, r1; int yl;
    if (y0 >= 0 && y0 <= H - 2)      { yl = y0;    r0 = 1.f - fy; r1 = fy;       }
    else if (y0 == -1)               { yl = 0;     r0 = fy;       r1 = 0.f;      }
    else if (y0 == H - 1)            { yl = H - 2; r0 = 0.f;      r1 = 1.f - fy; }
    else                             { yl = 0;     r0 = 0.f;      r1 = 0.f;      }
    float c0, c1; int xl;
    if (x0 >= 0 && x0 <= W - 2)      { xl = x0;    c0 = 1.f - fx; c1 = fx;       }
    else if (x0 == -1)               { xl = 0;     c0 = fx;       c1 = 0.f;      }
    else if (x0 == W - 1)            { xl = W - 2; c0 = 0.f;      c1 = 1.f - fx; }
    else                             { xl = 0;     c0 = 0.f;      c1 = 0.f;      }
    r0 *= m; r1 *= m;
    sbase[e] = ((yl << 6) + xl) << 8;
    s00[e] = r0 * c0; s01[e] = r0 * c1;
    s10[e] = r1 * c0; s11[e] = r1 * c1;
  }
  __syncthreads();   // also protects sm_om (aliases cols[0]) before tap-0 write

  // ======== Phase B: async-staged tap pipeline (1 barrier/tap)
  floatx4 acc[2][4];                     // [m within pair][n-tile]
#pragma unroll
  for (int a = 0; a < 2; ++a)
#pragma unroll
    for (int u = 0; u < 4; ++u) acc[a][u] = (floatx4){0.f, 0.f, 0.f, 0.f};

  int sn = tid >> 3;        // pixel 0..63
  int scb = tid & 7;        // c-block low bits

  // prologue: sample tap 0 into cols[0] (latency exposed once)
  {
    const unsigned short* p = xtb + sbase[sn];
    f32x2 w00 = (f32x2){s00[sn], s00[sn]};
    f32x2 w01 = (f32x2){s01[sn], s01[sn]};
    f32x2 w10 = (f32x2){s10[sn], s10[sn]};
    f32x2 w11 = (f32x2){s11[sn], s11[sn]};
    uintx4 u00[2], u01[2], u10[2], u11[2];
    issue_half(p, scb, 0, u00, u01, u10, u11);
    finish_half(cols[0], sn, scb, 0, w00, w01, w10, w11, u00, u01, u10, u11);
    issue_half(p, scb, 1, u00, u01, u10, u11);
    finish_half(cols[0], sn, scb, 1, w00, w01, w10, w11, u00, u01, u10, u11);
  }
  __syncthreads();

  for (int tap = 0; tap < 9; ++tap) {
    short* cur = cols[tap & 1];
    short* nxt = cols[(tap + 1) & 1];
    if (tap < 8) {
      int ei = (tap + 1) * 64 + sn;
      const unsigned short* p = xtb + sbase[ei];
      uintx4 u00[2], u01[2], u10[2], u11[2];
      // issue first half of next tap's corner loads, hide under MFMA
      issue_half(p, scb, 0, u00, u01, u10, u11);
      mfma_half(tap, 0, wb, cur, wvid, lane, q, lm, acc);
      f32x2 w00 = (f32x2){s00[ei], s00[ei]};
      f32x2 w01 = (f32x2){s01[ei], s01[ei]};
      f32x2 w10 = (f32x2){s10[ei], s10[ei]};
      f32x2 w11 = (f32x2){s11[ei], s11[ei]};
      finish_half(nxt, sn, scb, 0, w00, w01, w10, w11, u00, u01, u10, u11);
      issue_half(p, scb, 1, u00, u01, u10, u11);
      mfma_half(tap, 1, wb, cur, wvid, lane, q, lm, acc);
      finish_half(nxt, sn, scb, 1, w00, w01, w10, w11, u00, u01, u10, u11);
    } else {
      mfma_half(tap, 0, wb, cur, wvid, lane, q, lm, acc);
      mfma_half(tap, 1, wb, cur, wvid, lane, q, lm, acc);
    }
    __syncthreads();
  }

  // ---- epilogue: BN + ReLU + store ----
#pragma unroll
  for (int a = 0; a < 2; ++a) {
#pragma unroll
    for (int u = 0; u < 4; ++u) {
      int nn = u * 16 + lm;
#pragma unroll
      for (int r = 0; r < 4; ++r) {
        int o = (wvid * 2 + a) * 16 + q * 4 + r;
        float v = fmaf(acc[a][u][r], invsh[o], invsh[O + o]);
        out[((size_t)(b * O + o)) * HWSZ + h * W + nn] = fmaxf(v, 0.0f);
      }
    }
  }
}

extern "C" void kernel_launch(void* const* d_in, const int* in_sizes, int n_in,
                              void* d_out, int out_size, void* d_ws, size_t ws_size,
                              hipStream_t stream) {
  const float* x        = (const float*)d_in[0];
  const float* w_off    = (const float*)d_in[1];
  const float* b_off    = (const float*)d_in[2];
  const float* weight   = (const float*)d_in[3];
  const float* bias     = (const float*)d_in[4];
  const float* gamma    = (const float*)d_in[5];
  const float* beta     = (const float*)d_in[6];
  const float* run_mean = (const float*)d_in[7];
  const float* run_var  = (const float*)d_in[8];
  float* out = (float*)d_out;

  // workspace layout (~18.1 MB)
  char* ws = (char*)d_ws;
  unsigned short* xt = (unsigned short*)ws;                    // 16777216 B
  unsigned short* wbf = (unsigned short*)(ws + 16777216);      // 1179648 B
  unsigned short* wob = (unsigned short*)(ws + 17956864);      // 147456 B
  float* invsh = (float*)(ws + 18104320);                      // 2048 B

  prep_all2<<<419, 512, 0, stream>>>(x, weight, w_off, bias, gamma, beta,
                                     run_mean, run_var, xt, wbf, wob, invsh);
  {
    dim3 grid(NB, H);
    deform_mfma_kernel<<<grid, 512, 0, stream>>>(xt, wob, b_off, wbf, invsh, out);
  }
}

// Round 12
// 186.358 us; speedup vs baseline: 1.2399x; 1.2399x over previous
//
#include <hip/hip_runtime.h>
#include <math.h>

#define H 64
#define W 64
#define C 256
#define O 256
#define CK 2304
#define NB 8
#define HWSZ 4096            // H*W

typedef __attribute__((ext_vector_type(8))) short short8;
typedef __attribute__((ext_vector_type(4))) float floatx4;
typedef __attribute__((ext_vector_type(4))) unsigned uintx4;
typedef __attribute__((ext_vector_type(2))) float f32x2;

// swizzle giving uniform bank-group coverage in every 16-lane b128 phase
// for both the sampling-write map and the MFMA-read map
#define FSWZ(n) ((((n) & 3) << 1) | (((n) >> 2) & 1))

__device__ __forceinline__ float lo2f(unsigned u) {
  return __builtin_bit_cast(float, u << 16);
}
__device__ __forceinline__ float hi2f(unsigned u) {
  return __builtin_bit_cast(float, u & 0xffff0000u);
}
// unpack u32 of 2 bf16 -> f32x2 {lo, hi}
__device__ __forceinline__ f32x2 up2(unsigned u) {
  return (f32x2){lo2f(u), hi2f(u)};
}
// pack two fp32 -> bf16 pair, round-half-up (prep kernels)
__device__ __forceinline__ unsigned pk2bf(float v0, float v1) {
  unsigned a = __builtin_bit_cast(unsigned, v0);
  unsigned b = __builtin_bit_cast(unsigned, v1);
  return ((a + 0x8000u) >> 16) | ((b + 0x8000u) & 0xffff0000u);
}

// ---- packed fp32 math + hw bf16 pack (hipcc won't emit these itself) ----
__device__ __forceinline__ f32x2 pk_mul(f32x2 a, f32x2 b) {
  f32x2 d;
  asm("v_pk_mul_f32 %0, %1, %2" : "=v"(d) : "v"(a), "v"(b));
  return d;
}
__device__ __forceinline__ f32x2 pk_fma(f32x2 a, f32x2 b, f32x2 c) {
  f32x2 d;
  asm("v_pk_fma_f32 %0, %1, %2, %3" : "=v"(d) : "v"(a), "v"(b), "v"(c));
  return d;
}
__device__ __forceinline__ unsigned cvtpk(f32x2 a) {
  unsigned d;
  asm("v_cvt_pk_bf16_f32 %0, %1, %2" : "=v"(d) : "v"(a[0]), "v"(a[1]));
  return d;
}

// ---------------- prep_all2: transpose + weight packs + BN, ONE launch ----
// region 0: bid < 256 : transpose x NCHW fp32 -> NHWC bf16
// region 1: bid < 400 : prep main weight -> MFMA-A fragments
// region 2: bid < 418 : prep offset weight -> A fragments (M padded 27->32)
// region 3: bid ==418 : folded BN
__global__ __launch_bounds__(512) void prep_all2(
    const float* __restrict__ x, const float* __restrict__ weight,
    const float* __restrict__ w_off, const float* __restrict__ bias,
    const float* __restrict__ gamma, const float* __restrict__ beta,
    const float* __restrict__ run_mean, const float* __restrict__ run_var,
    unsigned short* __restrict__ xt, unsigned short* __restrict__ wb,
    unsigned short* __restrict__ wob, float* __restrict__ invsh) {
  __shared__ unsigned tile[16384];       // [2][128][64] u32, 64 KB
  int bid = blockIdx.x;
  int tid = threadIdx.x;

  if (bid < 256) {
    int b = bid >> 5;
    int yg = bid & 31;
    int y0 = yg * 2;
    // ---- phase 1: load ch-pair x 2 rows, pack bf16 pairs into LDS ----
#pragma unroll
    for (int j = 0; j < 4; ++j) {
      int e = tid + 512 * j;             // (cp 0..127) x (xx4 0..15)
      int xx4 = e & 15;
      int cp = e >> 4;
      const float* p0 = x + ((size_t)b * C + 2 * cp) * HWSZ + y0 * W + xx4 * 4;
      floatx4 f00 = *reinterpret_cast<const floatx4*>(p0);
      floatx4 f01 = *reinterpret_cast<const floatx4*>(p0 + W);
      floatx4 f10 = *reinterpret_cast<const floatx4*>(p0 + HWSZ);
      floatx4 f11 = *reinterpret_cast<const floatx4*>(p0 + HWSZ + W);
      int sw = cp & 31;
#pragma unroll
      for (int k = 0; k < 4; ++k) {
        int px = xx4 * 4 + k;
        tile[cp * 64 + (px ^ sw)] = pk2bf(f00[k], f10[k]);
        tile[8192 + cp * 64 + (px ^ sw)] = pk2bf(f01[k], f11[k]);
      }
    }
    __syncthreads();
    // ---- phase 2: contiguous 32 KB store of 2 full NHWC rows ----
    unsigned short* xo = xt + ((size_t)(b * 64 + y0) << 14);
#pragma unroll
    for (int j = 0; j < 8; ++j) {
      int e = tid + 512 * j;             // (r 0..1) x (xx 0..63) x (cq 0..31)
      int cq = e & 31;
      int xx = (e >> 5) & 63;
      int r = e >> 11;
      unsigned u[4];
#pragma unroll
      for (int kk = 0; kk < 4; ++kk) {
        int cpv = cq * 4 + kk;
        u[kk] = tile[r * 8192 + cpv * 64 + (xx ^ (cpv & 31))];
      }
      uint4 v = {u[0], u[1], u[2], u[3]};
      *reinterpret_cast<uint4*>(xo + (r << 14) + (xx << 8) + (cq << 3)) = v;
    }
  } else if (bid < 400) {
    int idx = (bid - 256) * 512 + tid;
    int d0 = idx * 8;
    int lane = idx & 63;
    int mt = (idx >> 6) & 15;
    int ks = idx >> 10;
    int o = mt * 16 + (lane & 15);
    int kn0 = ks * 32 + (lane >> 4) * 8;
    int tap = kn0 >> 8;
    int c0 = kn0 & 255;
    const float* wsrc = weight + o * CK + c0 * 9 + tap;
    unsigned pk[4];
#pragma unroll
    for (int p = 0; p < 4; ++p)
      pk[p] = pk2bf(wsrc[(2 * p) * 9], wsrc[(2 * p + 1) * 9]);
    uint4 v = {pk[0], pk[1], pk[2], pk[3]};
    *reinterpret_cast<uint4*>(wb + d0) = v;
  } else if (bid < 418) {
    int idx = (bid - 400) * 512 + tid;
    int d0 = idx * 8;
    int lane = idx & 63;
    int mt = (idx >> 6) & 1;
    int ks = idx >> 7;
    int o = mt * 16 + (lane & 15);
    int kn0 = ks * 32 + (lane >> 4) * 8;
    int tap = kn0 >> 8;
    int c0 = kn0 & 255;
    uint4 v;
    if (o < 27) {
      const float* wsrc = w_off + o * CK + c0 * 9 + tap;
      unsigned pk[4];
#pragma unroll
      for (int p = 0; p < 4; ++p)
        pk[p] = pk2bf(wsrc[(2 * p) * 9], wsrc[(2 * p + 1) * 9]);
      v = (uint4){pk[0], pk[1], pk[2], pk[3]};
    } else {
      v = (uint4){0, 0, 0, 0};
    }
    *reinterpret_cast<uint4*>(wob + d0) = v;
  } else {
    if (tid < 256) {
      int o = tid;
      float inv = gamma[o] * rsqrtf(run_var[o] + 1e-5f);
      invsh[o] = inv;
      invsh[O + o] = beta[o] + (bias[o] - run_mean[o]) * inv;
    }
  }
}

// ---------------- Fused kernel: offset conv + deform sample + GEMM + BN ---
// grid (b, h), 512 threads (8 waves).  Block = row h: 64 px x 256 out.
// Session-best structure (r8, 96.6 us): simple 2-barrier tap loop, packed
// f32 bilinear via v_pk_* asm, __launch_bounds__(512,2) register regime,
// 2 co-resident blocks/CU for cross-block phase overlap.  Four structural
// pipelining rewrites (role-split, dbuf, T14 x2) all measured slower —
// performance here = simple structure x 2 blocks/CU x compiler scheduling.
__global__ __launch_bounds__(512, 2) void deform_mfma_kernel(
    const unsigned short* __restrict__ xt, const unsigned short* __restrict__ wob,
    const float* __restrict__ b_off, const unsigned short* __restrict__ wb,
    const float* __restrict__ invsh, float* __restrict__ out) {
  __shared__ short cols[64 * 256];       // 32 KB, FSWZ-swizzled
  __shared__ float sm_om[27 * 64];       // offset-conv result for this row
  __shared__ int sbase[576];
  __shared__ float s00[576], s01[576], s10[576], s11[576];

  int tid = threadIdx.x;
  int lane = tid & 63;
  int wvid = tid >> 6;                   // 0..7
  int q = lane >> 4;
  int lm = lane & 15;
  int b = blockIdx.x;
  int h = blockIdx.y;
  const unsigned short* xtb = xt + ((size_t)b << 20);

  // ======== Phase A: offset conv, 4 active waves, wave = 1 mt x 2 nt
  if (wvid < 4) {
    int mt = wvid & 1;
    int nh = wvid >> 1;                  // px quarter-pair
    floatx4 a0[2];
    a0[0] = (floatx4){0.f, 0.f, 0.f, 0.f};
    a0[1] = (floatx4){0.f, 0.f, 0.f, 0.f};
    int pxu[2];
    pxu[0] = (nh * 2 + 0) * 16 + lm;
    pxu[1] = (nh * 2 + 1) * 16 + lm;
    for (int tap = 0; tap < 9; ++tap) {
      int yy = h - 1 + tap / 3;
      bool vy = (yy >= 0) && (yy < H);
      const unsigned short* bp[2];
      bool vv[2];
#pragma unroll
      for (int u = 0; u < 2; ++u) {
        int xx = pxu[u] - 1 + tap % 3;
        vv[u] = vy && (xx >= 0) && (xx < W);
        bp[u] = xtb + ((((yy & 63) << 6) + (xx & 63)) << 8) + q * 8;
      }
#pragma unroll
      for (int s = 0; s < 8; ++s) {
        int ks = tap * 8 + s;
        short8 afrag = *reinterpret_cast<const short8*>(
            wob + (((ks * 2 + mt) * 64 + lane) << 3));
#pragma unroll
        for (int u = 0; u < 2; ++u) {
          short8 bfrag;
          if (vv[u])
            bfrag = *reinterpret_cast<const short8*>(bp[u] + s * 32);
          else
            bfrag = (short8){0, 0, 0, 0, 0, 0, 0, 0};
          a0[u] = __builtin_amdgcn_mfma_f32_16x16x32_bf16(afrag, bfrag, a0[u], 0, 0, 0);
        }
      }
    }
#pragma unroll
    for (int u = 0; u < 2; ++u)
#pragma unroll
      for (int r = 0; r < 4; ++r) {
        int o = mt * 16 + q * 4 + r;
        if (o < 27) sm_om[o * 64 + pxu[u]] = a0[u][r] + b_off[o];
      }
  }
  __syncthreads();

  // ======== Phase A2: separable clamp-swap bilinear tables (9 taps x 64 px)
  for (int e = tid; e < 576; e += 512) {
    int n = e & 63;
    int k = e >> 6;
    float oy = sm_om[k * 64 + n];
    float ox = sm_om[(9 + k) * 64 + n];
    float mv = sm_om[(18 + k) * 64 + n];
    float m = 1.0f / (1.0f + __expf(-mv));
    float py = (float)(h - 1 + k / 3) + oy;
    float px = (float)(n - 1 + k % 3) + ox;
    float yf = floorf(py), xf = floorf(px);
    int y0 = (int)yf, x0 = (int)xf;
    float fy = py - yf, fx = px - xf;
    float r0, r1; int yl;
    if (y0 >= 0 && y0 <= H - 2)      { yl = y0;    r0 = 1.f - fy; r1 = fy;       }
    else if (y0 == -1)               { yl = 0;     r0 = fy;       r1 = 0.f;      }
    else if (y0 == H - 1)            { yl = H - 2; r0 = 0.f;      r1 = 1.f - fy; }
    else                             { yl = 0;     r0 = 0.f;      r1 = 0.f;      }
    float c0, c1; int xl;
    if (x0 >= 0 && x0 <= W - 2)      { xl = x0;    c0 = 1.f - fx; c1 = fx;       }
    else if (x0 == -1)               { xl = 0;     c0 = fx;       c1 = 0.f;      }
    else if (x0 == W - 1)            { xl = W - 2; c0 = 0.f;      c1 = 1.f - fx; }
    else                             { xl = 0;     c0 = 0.f;      c1 = 0.f;      }
    r0 *= m; r1 *= m;
    sbase[e] = ((yl << 6) + xl) << 8;
    s00[e] = r0 * c0; s01[e] = r0 * c1;
    s10[e] = r1 * c0; s11[e] = r1 * c1;
  }
  __syncthreads();

  // ======== Phase B: main deformable GEMM.  Wave = 2 m-tiles x 4 n-tiles
  floatx4 acc[2][4];                     // [m within pair][n-tile]
#pragma unroll
  for (int a = 0; a < 2; ++a)
#pragma unroll
    for (int u = 0; u < 4; ++u) acc[a][u] = (floatx4){0.f, 0.f, 0.f, 0.f};

  int sn = tid >> 3;        // pixel 0..63
  int scb = tid & 7;        // c-block low bits

  for (int tap = 0; tap < 9; ++tap) {
    if (tap) __syncthreads();
    // ---- sampling: 4 coalesced corner loads per c-block, packed bilinear
    {
      int ei = tap * 64 + sn;
      int base = sbase[ei];
      float w00 = s00[ei], w01 = s01[ei], w10 = s10[ei], w11 = s11[ei];
      f32x2 W00 = (f32x2){w00, w00};
      f32x2 W01 = (f32x2){w01, w01};
      f32x2 W10 = (f32x2){w10, w10};
      f32x2 W11 = (f32x2){w11, w11};
      const unsigned short* p = xtb + base;
#pragma unroll
      for (int i = 0; i < 4; ++i) {
        int cbw = (i << 3) | scb;
        int co = cbw << 3;
        uintx4 u00 = *reinterpret_cast<const uintx4*>(p + co);
        uintx4 u01 = *reinterpret_cast<const uintx4*>(p + 256 + co);
        uintx4 u10 = *reinterpret_cast<const uintx4*>(p + 16384 + co);
        uintx4 u11 = *reinterpret_cast<const uintx4*>(p + 16640 + co);
        uintx4 res;
#pragma unroll
        for (int jd = 0; jd < 4; ++jd) {
          f32x2 a = pk_mul(up2(u00[jd]), W00);
          a = pk_fma(up2(u01[jd]), W01, a);
          a = pk_fma(up2(u10[jd]), W10, a);
          a = pk_fma(up2(u11[jd]), W11, a);
          res[jd] = cvtpk(a);
        }
        int pos = (cbw ^ FSWZ(sn)) & 31;
        *reinterpret_cast<uintx4*>(&cols[(sn << 8) + (pos << 3)]) = res;
      }
    }
    __syncthreads();

    // ---- MFMA: 8 k-steps, 2 m-tiles x 4 n-tiles per wave ----
#pragma unroll
    for (int s = 0; s < 8; ++s) {
      int ks = tap * 8 + s;
      short8 afrag[2];
#pragma unroll
      for (int a = 0; a < 2; ++a)
        afrag[a] = *reinterpret_cast<const short8*>(
            wb + (((ks * 16 + wvid * 2 + a) * 64 + lane) << 3));
      short8 bfrag[4];
#pragma unroll
      for (int u = 0; u < 4; ++u) {
        int nn = u * 16 + lm;
        int pos = ((s * 4 + q) ^ FSWZ(nn)) & 31;
        bfrag[u] = *reinterpret_cast<const short8*>(&cols[(nn << 8) + (pos << 3)]);
      }
#pragma unroll
      for (int a = 0; a < 2; ++a)
#pragma unroll
        for (int u = 0; u < 4; ++u)
          acc[a][u] = __builtin_amdgcn_mfma_f32_16x16x32_bf16(
              afrag[a], bfrag[u], acc[a][u], 0, 0, 0);
    }
  }

  // ---- epilogue: BN + ReLU + store ----
#pragma unroll
  for (int a = 0; a < 2; ++a) {
#pragma unroll
    for (int u = 0; u < 4; ++u) {
      int nn = u * 16 + lm;
#pragma unroll
      for (int r = 0; r < 4; ++r) {
        int o = (wvid * 2 + a) * 16 + q * 4 + r;
        float v = fmaf(acc[a][u][r], invsh[o], invsh[O + o]);
        out[((size_t)(b * O + o)) * HWSZ + h * W + nn] = fmaxf(v, 0.0f);
      }
    }
  }
}

extern "C" void kernel_launch(void* const* d_in, const int* in_sizes, int n_in,
                              void* d_out, int out_size, void* d_ws, size_t ws_size,
                              hipStream_t stream) {
  const float* x        = (const float*)d_in[0];
  const float* w_off    = (const float*)d_in[1];
  const float* b_off    = (const float*)d_in[2];
  const float* weight   = (const float*)d_in[3];
  const float* bias     = (const float*)d_in[4];
  const float* gamma    = (const float*)d_in[5];
  const float* beta     = (const float*)d_in[6];
  const float* run_mean = (const float*)d_in[7];
  const float* run_var  = (const float*)d_in[8];
  float* out = (float*)d_out;

  // workspace layout (~18.1 MB)
  char* ws = (char*)d_ws;
  unsigned short* xt = (unsigned short*)ws;                    // 16777216 B
  unsigned short* wbf = (unsigned short*)(ws + 16777216);      // 1179648 B
  unsigned short* wob = (unsigned short*)(ws + 17956864);      // 147456 B
  float* invsh = (float*)(ws + 18104320);                      // 2048 B

  prep_all2<<<419, 512, 0, stream>>>(x, weight, w_off, bias, gamma, beta,
                                     run_mean, run_var, xt, wbf, wob, invsh);
  {
    dim3 grid(NB, H);
    deform_mfma_kernel<<<grid, 512, 0, stream>>>(xt, wob, b_off, wbf, invsh, out);
  }
}